// Round 1
// baseline (378.721 us; speedup 1.0000x reference)
//
#include <hip/hip_runtime.h>
#include <math.h>

// Problem constants: x [16,64,256,256] f32, mask [16,256,256] i32
#define BATCH 16
#define CH    64
#define HW    65536          // 256*256
#define HW4   16384          // HW/4 (float4 units)

// ws layout (floats): [0..16) cnt[b]; [16..64) S1[b*3+c]; [64..112) S2[b*3+c];
// [112..160) mean[b*3+c]; [160..208) rstd[b*3+c]
#define ACC_CNT  0
#define ACC_S1   16
#define ACC_S2   64
#define ACC_MEAN 112
#define ACC_RSTD 160

__global__ __launch_bounds__(256) void pool_stats_kernel(
    const float* __restrict__ x, const int* __restrict__ mask,
    float* __restrict__ out, float* __restrict__ acc)
{
    // 64 blocks per batch image; each block covers 1024 pixels (4/thread)
    const int b    = blockIdx.x >> 6;
    const int pblk = blockIdx.x & 63;
    const int idx4 = pblk * 256 + threadIdx.x;          // float4 index in [0, HW4)

    const float4* xb = (const float4*)x + (size_t)b * CH * HW4;

    float4 v = xb[idx4];
    float4 vmax = v, vmin = v, vsum = v;
#pragma unroll 8
    for (int c = 1; c < CH; ++c) {
        float4 t = xb[(size_t)c * HW4 + idx4];
        vmax.x = fmaxf(vmax.x, t.x); vmax.y = fmaxf(vmax.y, t.y);
        vmax.z = fmaxf(vmax.z, t.z); vmax.w = fmaxf(vmax.w, t.w);
        vmin.x = fminf(vmin.x, t.x); vmin.y = fminf(vmin.y, t.y);
        vmin.z = fminf(vmin.z, t.z); vmin.w = fminf(vmin.w, t.w);
        vsum.x += t.x; vsum.y += t.y; vsum.z += t.z; vsum.w += t.w;
    }
    const float inv = 1.0f / 64.0f;
    float4 vmean = make_float4(vsum.x * inv, vsum.y * inv, vsum.z * inv, vsum.w * inv);

    // write pooled channels [max, mean, min] directly into d_out [B,3,H,W]
    float4* ob = (float4*)out + (size_t)b * 3 * HW4;
    ob[idx4]           = vmax;
    ob[HW4 + idx4]     = vmean;
    ob[2 * HW4 + idx4] = vmin;

    // masked partial sums for this thread's 4 pixels
    int4 mk = ((const int4*)mask)[(size_t)b * HW4 + idx4];
    float vals[7] = {0.f, 0.f, 0.f, 0.f, 0.f, 0.f, 0.f}; // cnt, S1[3], S2[3]
    if (mk.x == 1) { vals[0] += 1.f;
        vals[1] += vmax.x;  vals[4] += vmax.x  * vmax.x;
        vals[2] += vmean.x; vals[5] += vmean.x * vmean.x;
        vals[3] += vmin.x;  vals[6] += vmin.x  * vmin.x; }
    if (mk.y == 1) { vals[0] += 1.f;
        vals[1] += vmax.y;  vals[4] += vmax.y  * vmax.y;
        vals[2] += vmean.y; vals[5] += vmean.y * vmean.y;
        vals[3] += vmin.y;  vals[6] += vmin.y  * vmin.y; }
    if (mk.z == 1) { vals[0] += 1.f;
        vals[1] += vmax.z;  vals[4] += vmax.z  * vmax.z;
        vals[2] += vmean.z; vals[5] += vmean.z * vmean.z;
        vals[3] += vmin.z;  vals[6] += vmin.z  * vmin.z; }
    if (mk.w == 1) { vals[0] += 1.f;
        vals[1] += vmax.w;  vals[4] += vmax.w  * vmax.w;
        vals[2] += vmean.w; vals[5] += vmean.w * vmean.w;
        vals[3] += vmin.w;  vals[6] += vmin.w  * vmin.w; }

    // wave (64-lane) shuffle reduction
    for (int off = 32; off > 0; off >>= 1) {
#pragma unroll
        for (int k = 0; k < 7; ++k)
            vals[k] += __shfl_down(vals[k], off, 64);
    }

    // cross-wave (4 waves) LDS reduction, then 7 atomics per block
    __shared__ float red[4][8];
    const int lane = threadIdx.x & 63;
    const int wid  = threadIdx.x >> 6;
    if (lane == 0) {
#pragma unroll
        for (int k = 0; k < 7; ++k) red[wid][k] = vals[k];
    }
    __syncthreads();
    if (threadIdx.x < 7) {
        const int k = threadIdx.x;
        float s = red[0][k] + red[1][k] + red[2][k] + red[3][k];
        int off;
        if (k == 0)      off = ACC_CNT + b;
        else if (k < 4)  off = ACC_S1 + b * 3 + (k - 1);
        else             off = ACC_S2 + b * 3 + (k - 4);
        atomicAdd(&acc[off], s);
    }
}

__global__ void finalize_kernel(float* __restrict__ acc)
{
    const int t = threadIdx.x;
    if (t < BATCH * 3) {
        const int b = t / 3;
        const float cnt = acc[ACC_CNT + b];
        const float S1  = acc[ACC_S1 + t];
        const float S2  = acc[ACC_S2 + t];
        const float mean = S1 / cnt;
        const float var  = (S2 - S1 * S1 / cnt) / (cnt - 1.0f);
        acc[ACC_MEAN + t] = mean;
        acc[ACC_RSTD + t] = 1.0f / sqrtf(var);
    }
}

__global__ __launch_bounds__(256) void norm_kernel(
    float* __restrict__ out, const int* __restrict__ mask,
    const float* __restrict__ acc)
{
    const int i4   = blockIdx.x * 256 + threadIdx.x;   // [0, 3*B*HW4)
    const int bc   = i4 >> 14;                         // / HW4
    const int idx4 = i4 & (HW4 - 1);
    const int b    = bc / 3;                           // compiler magic-mul

    const float mean = acc[ACC_MEAN + bc];
    const float rstd = acc[ACC_RSTD + bc];

    float4 v = ((const float4*)out)[i4];
    int4 mk  = ((const int4*)mask)[(size_t)b * HW4 + idx4];
    v.x = (mk.x == 1) ? (v.x - mean) * rstd : 0.0f;
    v.y = (mk.y == 1) ? (v.y - mean) * rstd : 0.0f;
    v.z = (mk.z == 1) ? (v.z - mean) * rstd : 0.0f;
    v.w = (mk.w == 1) ? (v.w - mean) * rstd : 0.0f;
    ((float4*)out)[i4] = v;
}

extern "C" void kernel_launch(void* const* d_in, const int* in_sizes, int n_in,
                              void* d_out, int out_size, void* d_ws, size_t ws_size,
                              hipStream_t stream)
{
    const float* x    = (const float*)d_in[0];
    const int*   mask = (const int*)d_in[1];
    float*       out  = (float*)d_out;
    float*       acc  = (float*)d_ws;

    // zero the 112 accumulator floats (ws is re-poisoned to 0xAA every call)
    hipMemsetAsync(d_ws, 0, 112 * sizeof(float), stream);

    pool_stats_kernel<<<BATCH * 64, 256, 0, stream>>>(x, mask, out, acc);
    finalize_kernel<<<1, 64, 0, stream>>>(acc);
    norm_kernel<<<3 * BATCH * HW4 / 256, 256, 0, stream>>>(out, mask, acc);
}